// Round 1
// baseline (1371.043 us; speedup 1.0000x reference)
//
#include <hip/hip_runtime.h>

// Problem constants (fixed by reference):
#define F_DIM  4096
#define NROUNDS 12
#define NBLK   2048
#define GM     8192   // B*S
#define GN     4096   // F_OUT
#define GK     4096   // F_IN

typedef short short8 __attribute__((ext_vector_type(8)));
typedef float f32x4  __attribute__((ext_vector_type(4)));
typedef unsigned short us8 __attribute__((ext_vector_type(8)));
typedef unsigned short ushortT;

typedef __attribute__((address_space(3))) void lds_void;
typedef const __attribute__((address_space(1))) void glob_void;

// ---- ordered-uint encoding for float atomics (monotone map float -> uint) ----
__device__ __forceinline__ unsigned ordf(float f) {
    unsigned u = __float_as_uint(f);
    return (u & 0x80000000u) ? ~u : (u | 0x80000000u);
}
__device__ __forceinline__ float unordf(unsigned u) {
    unsigned v = (u & 0x80000000u) ? (u & 0x7fffffffu) : ~u;
    return __uint_as_float(v);
}
// RNE float -> bf16 bits (no NaN/inf in this problem)
__device__ __forceinline__ ushortT f2bf(float f) {
    unsigned u = __float_as_uint(f);
    return (ushortT)((u + 0x7fffu + ((u >> 16) & 1u)) >> 16);
}

__global__ void init_mm_kernel(unsigned* mm) {
    // mm[0]=xmin, mm[1]=xmax, mm[2]=wmin, mm[3]=wmax (ordered-uint)
    if (threadIdx.x < 4) mm[threadIdx.x] = (threadIdx.x & 1) ? 0u : 0xFFFFFFFFu;
}

// Rotate 4 rows per block through 12 permute+2x2 rounds, in-place in LDS.
// QUANT=false: reduce global min/max (atomics on ordered uints).
// QUANT=true : recompute rotation, quantize-dequantize, store bf16 (ushort).
template <bool QUANT>
__global__ __launch_bounds__(256)
void rotate_kernel(const float* __restrict__ src,
                   const int*   __restrict__ perms,
                   const float* __restrict__ mats,
                   unsigned*    __restrict__ mm,
                   ushortT*     __restrict__ dst)
{
    constexpr int R = 4;
    __shared__ alignas(16) float buf[R][F_DIM];   // 64 KB
    const int t = threadIdx.x;
    const size_t r0 = (size_t)blockIdx.x * R;

    // load 4 rows, coalesced float4
    #pragma unroll
    for (int i = 0; i < R; ++i) {
        const float4* s4 = (const float4*)(src + (r0 + i) * F_DIM);
        #pragma unroll
        for (int q = 0; q < 4; ++q)
            ((float4*)buf[i])[t + q * 256] = s4[t + q * 256];
    }
    __syncthreads();

    #pragma unroll 1
    for (int r = 0; r < NROUNDS; ++r) {
        // round metadata into registers: thread t owns k-blocks t+q*256
        int2   p[8];
        float4 mt[8];
        const int2*   pr = (const int2*)(perms + (size_t)r * F_DIM);
        const float4* mr = (const float4*)(mats + (size_t)r * NBLK * 4);
        #pragma unroll
        for (int q = 0; q < 8; ++q) { int k = t + q * 256; p[q] = pr[k]; mt[q] = mr[k]; }

        #pragma unroll
        for (int i = 0; i < R; ++i) {
            float2 v[8];
            #pragma unroll
            for (int q = 0; q < 8; ++q)
                v[q] = make_float2(buf[i][p[q].x], buf[i][p[q].y]);
            __syncthreads();   // all reads of row i done before in-place writes
            #pragma unroll
            for (int q = 0; q < 8; ++q) {
                int k = t + q * 256;
                ((float2*)buf[i])[k] =
                    make_float2(mt[q].x * v[q].x + mt[q].y * v[q].y,
                                mt[q].z * v[q].x + mt[q].w * v[q].y);
            }
            __syncthreads();
        }
    }

    const int lane = t & 63;
    if (!QUANT) {
        float lmin = __FLT_MAX__, lmax = -__FLT_MAX__;
        #pragma unroll
        for (int i = 0; i < R; ++i) {
            #pragma unroll
            for (int q = 0; q < 16; ++q) {
                float vv = buf[i][t + q * 256];
                lmin = fminf(lmin, vv);
                lmax = fmaxf(lmax, vv);
            }
        }
        #pragma unroll
        for (int off = 32; off > 0; off >>= 1) {
            lmin = fminf(lmin, __shfl_down(lmin, off));
            lmax = fmaxf(lmax, __shfl_down(lmax, off));
        }
        if (lane == 0) {
            atomicMin(&mm[0], ordf(lmin));
            atomicMax(&mm[1], ordf(lmax));
        }
    } else {
        const float lo = unordf(mm[0]);
        const float hi = unordf(mm[1]);
        const float scale = (hi - lo) * (1.0f / 255.0f);
        const float inv   = 255.0f / (hi - lo);
        #pragma unroll
        for (int i = 0; i < R; ++i) {
            ushortT* drow = dst + (r0 + i) * F_DIM;
            #pragma unroll
            for (int q = 0; q < 2; ++q) {
                const int e = t + q * 256;       // 8-element chunk id
                const int j0 = e * 8;
                float4 v0 = ((const float4*)buf[i])[e * 2 + 0];
                float4 v1 = ((const float4*)buf[i])[e * 2 + 1];
                float vv[8] = {v0.x, v0.y, v0.z, v0.w, v1.x, v1.y, v1.z, v1.w};
                us8 pk;
                #pragma unroll
                for (int j = 0; j < 8; ++j) {
                    float qv = rintf((vv[j] - lo) * inv);
                    qv = fminf(fmaxf(qv, 0.0f), 255.0f);
                    pk[j] = f2bf(qv * scale + lo);
                }
                *(us8*)(drow + j0) = pk;
            }
        }
    }
}

// C = A(MxK,bf16) * B(NxK,bf16)^T + bias, fp32 out. 128x128 tile, BK=32,
// 4 waves each 64x64 via 4x4 of mfma_f32_16x16x32_bf16. global_load_lds
// width-16 staging, chunk-major LDS (slot = kchunk*128 + row -> 2-way free).
__global__ __launch_bounds__(256)
void gemm_bias_kernel(const ushortT* __restrict__ A,
                      const ushortT* __restrict__ B,
                      const float*   __restrict__ bias,
                      float*         __restrict__ C)
{
    __shared__ alignas(16) ushortT As[128 * 32];  // 8 KB
    __shared__ alignas(16) ushortT Bs[128 * 32];  // 8 KB
    const int t = threadIdx.x;
    const int mb = blockIdx.x, nb = blockIdx.y;
    const int lane = t & 63, wv = t >> 6;
    const int wm = (wv & 1) * 64, wn = (wv >> 1) * 64;
    const int rr = lane & 15, kc = lane >> 4;

    // staging: slot s in [0,512): row = s&127, kchunk = s>>7 (8 bf16 each)
    const int s0 = t, s1 = 256 + t;
    const ushortT* ga0 = A + ((size_t)(mb * 128 + (s0 & 127)) * GK + (s0 >> 7) * 8);
    const ushortT* ga1 = A + ((size_t)(mb * 128 + (s1 & 127)) * GK + (s1 >> 7) * 8);
    const ushortT* gb0 = B + ((size_t)(nb * 128 + (s0 & 127)) * GK + (s0 >> 7) * 8);
    const ushortT* gb1 = B + ((size_t)(nb * 128 + (s1 & 127)) * GK + (s1 >> 7) * 8);

    // wave-uniform LDS bases; HW writes base + lane*16
    lds_void* la0 = (lds_void*)&As[(wv * 64) * 8];
    lds_void* la1 = (lds_void*)&As[(256 + wv * 64) * 8];
    lds_void* lb0 = (lds_void*)&Bs[(wv * 64) * 8];
    lds_void* lb1 = (lds_void*)&Bs[(256 + wv * 64) * 8];

    f32x4 acc[4][4];
    const f32x4 zz = {0.f, 0.f, 0.f, 0.f};
    #pragma unroll
    for (int mi = 0; mi < 4; ++mi)
        #pragma unroll
        for (int ni = 0; ni < 4; ++ni)
            acc[mi][ni] = zz;

    #pragma unroll 1
    for (int k0 = 0; k0 < GK; k0 += 32) {
        __builtin_amdgcn_global_load_lds((glob_void*)ga0, la0, 16, 0, 0);
        __builtin_amdgcn_global_load_lds((glob_void*)ga1, la1, 16, 0, 0);
        __builtin_amdgcn_global_load_lds((glob_void*)gb0, lb0, 16, 0, 0);
        __builtin_amdgcn_global_load_lds((glob_void*)gb1, lb1, 16, 0, 0);
        ga0 += 32; ga1 += 32; gb0 += 32; gb1 += 32;
        __syncthreads();

        short8 af[4], bf[4];
        #pragma unroll
        for (int mi = 0; mi < 4; ++mi)
            af[mi] = *(const short8*)&As[(kc * 128 + wm + mi * 16 + rr) * 8];
        #pragma unroll
        for (int ni = 0; ni < 4; ++ni)
            bf[ni] = *(const short8*)&Bs[(kc * 128 + wn + ni * 16 + rr) * 8];

        #pragma unroll
        for (int mi = 0; mi < 4; ++mi)
            #pragma unroll
            for (int ni = 0; ni < 4; ++ni)
                acc[mi][ni] = __builtin_amdgcn_mfma_f32_16x16x32_bf16(
                    af[mi], bf[ni], acc[mi][ni], 0, 0, 0);
        __syncthreads();
    }

    float bv[4];
    #pragma unroll
    for (int ni = 0; ni < 4; ++ni)
        bv[ni] = bias[nb * 128 + wn + ni * 16 + rr];

    // C/D layout: row-in-16 = kc*4 + reg, col-in-16 = rr
    #pragma unroll
    for (int mi = 0; mi < 4; ++mi) {
        #pragma unroll
        for (int ni = 0; ni < 4; ++ni) {
            const int col = nb * 128 + wn + ni * 16 + rr;
            #pragma unroll
            for (int r = 0; r < 4; ++r) {
                const int row = mb * 128 + wm + mi * 16 + kc * 4 + r;
                C[(size_t)row * GN + col] = acc[mi][ni][r] + bv[ni];
            }
        }
    }
}

extern "C" void kernel_launch(void* const* d_in, const int* in_sizes, int n_in,
                              void* d_out, int out_size, void* d_ws, size_t ws_size,
                              hipStream_t stream)
{
    (void)in_sizes; (void)n_in; (void)out_size; (void)ws_size;
    const float* x     = (const float*)d_in[0];
    const float* w     = (const float*)d_in[1];
    const float* bias  = (const float*)d_in[2];
    const float* mats  = (const float*)d_in[3];
    const int*   perms = (const int*)d_in[4];
    float* out = (float*)d_out;

    char* ws = (char*)d_ws;
    ushortT*  xq = (ushortT*)ws;                                    // 64 MiB
    ushortT*  wq = (ushortT*)(ws + (size_t)GM * GK * 2);            // 32 MiB
    unsigned* mm = (unsigned*)(ws + (size_t)GM * GK * 2 + (size_t)GN * GK * 2);

    init_mm_kernel<<<1, 64, 0, stream>>>(mm);
    // pass 1: rotate + global min/max
    rotate_kernel<false><<<GM / 4, 256, 0, stream>>>(x, perms, mats, mm + 0, nullptr);
    rotate_kernel<false><<<GN / 4, 256, 0, stream>>>(w, perms, mats, mm + 2, nullptr);
    // pass 2: rotate + quant-dequant -> bf16 operands
    rotate_kernel<true><<<GM / 4, 256, 0, stream>>>(x, perms, mats, mm + 0, xq);
    rotate_kernel<true><<<GN / 4, 256, 0, stream>>>(w, perms, mats, mm + 2, wq);
    // GEMM + bias
    gemm_bias_kernel<<<dim3(GM / 128, GN / 128), 256, 0, stream>>>(xq, wq, bias, out);
}